// Round 11
// baseline (402.743 us; speedup 1.0000x reference)
//
#include <hip/hip_runtime.h>
#include <hip/hip_bf16.h>
#include <cstddef>

#define NB 4
#define NN 512
#define NH 256
#define NHEADS 8
#define NSUBH 32
#define NFF 1024
#define LNEPS 1e-5f

using short8 = __attribute__((ext_vector_type(8))) short;
using f32x4  = __attribute__((ext_vector_type(4))) float;
using fvec4  = __attribute__((ext_vector_type(4))) float;

__device__ __forceinline__ unsigned short f2bf(float x) {
    __hip_bfloat16 h = __float2bfloat16(x);          // HW RNE cvt
    return *reinterpret_cast<unsigned short*>(&h);
}

// ---------------------------------------------------------------------------
// Kernel A: V projection (blocks 0..255) + Wqk bf16 B-frag pack (block 256).
// ---------------------------------------------------------------------------
__global__ __launch_bounds__(256) void vproj_kernel(
    const float* __restrict__ S, const float* __restrict__ Wv,
    const float* __restrict__ bv, float* __restrict__ v_ws,
    const float* __restrict__ Wqk, short8* __restrict__ wqk_bf)
{
    const int t = threadIdx.x;
    if (blockIdx.x == NB * NN / 8) {
        // pack Wqk: wqk_bf[ks*64+lane] = B-frag (col n=lane&15, k-slice)
        if (t < 64) {
            const int lane = t;
            const int n = lane & 15;
            #pragma unroll
            for (int ks = 0; ks < 8; ++ks) {
                short8 v;
                #pragma unroll
                for (int q = 0; q < 8; ++q) {
                    const int k = ks * 32 + ((lane >> 4) & 3) * 8 + q;
                    v[q] = (n < 8) ? (short)f2bf(Wqk[k * NHEADS + n]) : (short)0;
                }
                wqk_bf[ks * 64 + lane] = v;
            }
        }
        return;
    }

    __shared__ float srow[8][NH];
    const int row0 = blockIdx.x * 8;
    #pragma unroll
    for (int r = 0; r < 8; ++r) srow[r][t] = S[(size_t)(row0 + r) * NH + t];
    __syncthreads();

    float acc[8];
    #pragma unroll
    for (int r = 0; r < 8; ++r) acc[r] = 0.0f;
    for (int e = 0; e < NH; e += 4) {
        const float w0 = Wv[(size_t)(e + 0) * NH + t];
        const float w1 = Wv[(size_t)(e + 1) * NH + t];
        const float w2 = Wv[(size_t)(e + 2) * NH + t];
        const float w3 = Wv[(size_t)(e + 3) * NH + t];
        #pragma unroll
        for (int r = 0; r < 8; ++r) {
            const float4 x4 = *(const float4*)&srow[r][e];
            acc[r] = fmaf(x4.x, w0, fmaf(x4.y, w1, fmaf(x4.z, w2, fmaf(x4.w, w3, acc[r]))));
        }
    }
    const float bvc = bv[t];
    const int h = t >> 5, d = t & 31;
    const int b = row0 / NN;
    const int jbase = row0 & (NN - 1);
    #pragma unroll
    for (int r = 0; r < 8; ++r)
        v_ws[((size_t)(b * NHEADS + h) * NN + (size_t)(jbase + r)) * NSUBH + d] = acc[r] + bvc;
}

// ---------------------------------------------------------------------------
// Kernel B1 (round-9 proven form): raw scores via MFMA — wave-autonomous,
// NT loads, coalesced 1KB-row loads, wave-private XOR-swizzled LDS slice,
// zero __syncthreads.
// ---------------------------------------------------------------------------
__global__ __launch_bounds__(256, 4) void scores_kernel(
    const float* __restrict__ T, const short8* __restrict__ wqk_bf,
    float* __restrict__ scores)
{
    __shared__ unsigned short tlds[64 * 256];   // 32 KB bf16 T-tile
    const int t = threadIdx.x;
    const int lane = t & 63, wv = t >> 6;
    const int bi = blockIdx.x >> 3;             // b*512 + i
    const int jt = blockIdx.x & 7;
    const int jbase = jt * 64;

    const fvec4* Tv = (const fvec4*)(T + ((size_t)bi * NN + jbase) * NH);

    // 1. issue 16 dense row-loads, non-temporal (1KB contiguous per instr)
    fvec4 ga[16];
    #pragma unroll
    for (int i = 0; i < 16; ++i)
        ga[i] = __builtin_nontemporal_load(&Tv[(size_t)(16 * wv + i) * 64 + lane]);

    // 2. B-fragments from pre-packed global (L2-hot) while T-loads fly
    short8 bfrag[8];
    #pragma unroll
    for (int ks = 0; ks < 8; ++ks) bfrag[ks] = wqk_bf[ks * 64 + lane];

    // 3. convert + stage wave-private rows (uniform row per instr, 512B dense)
    #pragma unroll
    for (int i = 0; i < 16; ++i) {
        const int row = 16 * wv + i;
        unsigned short v[4];
        v[0] = f2bf(ga[i][0]); v[1] = f2bf(ga[i][1]);
        v[2] = f2bf(ga[i][2]); v[3] = f2bf(ga[i][3]);
        const int byte = (row * 512 + lane * 8) ^ ((row & 7) << 4);
        *(uint2*)((char*)tlds + byte) = *(const uint2*)v;
    }

    // 4. K-loop: 8 x mfma 16x16x32 on own rows (lgkmcnt ordering, no barrier)
    f32x4 acc = {0.0f, 0.0f, 0.0f, 0.0f};
    const int jr = 16 * wv + (lane & 15);
    #pragma unroll
    for (int ks = 0; ks < 8; ++ks) {
        const int byte = (jr * 512 + ks * 64 + (lane >> 4) * 16) ^ ((jr & 7) << 4);
        const short8 af = *(const short8*)((const char*)tlds + byte);
        acc = __builtin_amdgcn_mfma_f32_16x16x32_bf16(af, bfrag[ks], acc, 0, 0, 0);
    }

    // 5. store raw scores: lane holds col h=lane&15 (<8 valid), 4 j-rows
    const int h = lane & 15;
    if (h < 8) {
        const int b = bi >> 9, i = bi & (NN - 1);
        const int j0 = jbase + 16 * wv + (lane >> 4) * 4;
        float4 st;
        st.x = acc[0]; st.y = acc[1]; st.z = acc[2]; st.w = acc[3];
        *(float4*)&scores[((size_t)(b * NHEADS + h) * NN + i) * NN + j0] = st;
    }
}

// ---------------------------------------------------------------------------
// Kernel B2: softmax (+mask) -> attn (NT store) + ctx (float4 partials).
// grid = B*N blocks, 256 threads.
// ---------------------------------------------------------------------------
__global__ __launch_bounds__(256) void softmax_ctx_kernel(
    const int* __restrict__ masks, const float* __restrict__ v_ws,
    float* __restrict__ attn, float* __restrict__ ctx_out)
{
    __shared__ float sc[NN][9];
    __shared__ float maddv[NN];
    __shared__ float cpart[4][NHEADS][NSUBH];
    const int t = threadIdx.x;
    const int b = blockIdx.x >> 9;
    const int i = blockIdx.x & (NN - 1);

    const int mi = masks[b * NN + i];
    for (int j = t; j < NN; j += 256)
        maddv[j] = (mi != 0 && masks[b * NN + j] != 0) ? 0.0f : -1000.0f;
    __syncthreads();

    // -------- softmax: 32 threads per head --------
    const int h = t >> 5;
    const int l32 = t & 31;
    float* srow = attn + ((size_t)(b * NHEADS + h) * NN + i) * NN;

    float vals[16];
    float m = -1e30f;
    #pragma unroll
    for (int k = 0; k < 4; ++k) {
        const int j0 = 4 * l32 + 128 * k;
        float4 s4 = *(const float4*)&srow[j0];
        const float4 m4 = *(const float4*)&maddv[j0];
        s4.x += m4.x; s4.y += m4.y; s4.z += m4.z; s4.w += m4.w;
        vals[4 * k + 0] = s4.x; vals[4 * k + 1] = s4.y;
        vals[4 * k + 2] = s4.z; vals[4 * k + 3] = s4.w;
        m = fmaxf(m, fmaxf(fmaxf(s4.x, s4.y), fmaxf(s4.z, s4.w)));
    }
    #pragma unroll
    for (int off = 16; off >= 1; off >>= 1) m = fmaxf(m, __shfl_xor(m, off, 32));
    float sum = 0.0f;
    #pragma unroll
    for (int k = 0; k < 16; ++k) {
        const float e = __expf(vals[k] - m);
        vals[k] = e;
        sum += e;
    }
    #pragma unroll
    for (int off = 16; off >= 1; off >>= 1) sum += __shfl_xor(sum, off, 32);
    const float inv = 1.0f / sum;
    #pragma unroll
    for (int k = 0; k < 4; ++k) {
        const int j0 = 4 * l32 + 128 * k;
        fvec4 p4;
        p4[0] = vals[4 * k + 0] * inv; p4[1] = vals[4 * k + 1] * inv;
        p4[2] = vals[4 * k + 2] * inv; p4[3] = vals[4 * k + 3] * inv;
        __builtin_nontemporal_store(p4, (fvec4*)&srow[j0]);
        sc[j0 + 0][h] = p4[0]; sc[j0 + 1][h] = p4[1];
        sc[j0 + 2][h] = p4[2]; sc[j0 + 3][h] = p4[3];
    }
    __syncthreads();

    // -------- ctx: thread (h2, dg, jq) sums a j-quarter with float4 loads ----
    const int h2 = t & 7, dg = (t >> 3) & 7, jq = t >> 6;
    const float* vbase = v_ws + (size_t)(b * NHEADS + h2) * NN * NSUBH + dg * 4;
    float4 pacc = make_float4(0.0f, 0.0f, 0.0f, 0.0f);
    #pragma unroll 8
    for (int j = jq * 128; j < jq * 128 + 128; ++j) {
        const float p = sc[j][h2];
        const float4 v4 = *(const float4*)(vbase + (size_t)j * NSUBH);
        pacc.x = fmaf(p, v4.x, pacc.x);
        pacc.y = fmaf(p, v4.y, pacc.y);
        pacc.z = fmaf(p, v4.z, pacc.z);
        pacc.w = fmaf(p, v4.w, pacc.w);
    }
    *(float4*)&cpart[jq][h2][dg * 4] = pacc;
    __syncthreads();

    // reduce 4 partials; thread -> (h, d)
    const int d = l32;
    const float s = cpart[0][h][d] + cpart[1][h][d] + cpart[2][h][d] + cpart[3][h][d];
    ctx_out[(size_t)(b * NN + i) * NH + h * NSUBH + d] = s;
}

// ---------------------------------------------------------------------------
// Kernel C: tail. x=relu(ctx·Wo+bo); x1=LN(S+x); y=relu(x1·W1+b1)·W2+b2;
// out=LN(x1+y). 8 rows per block, 256 blocks, 256 threads. NT out stores.
// ---------------------------------------------------------------------------
__global__ __launch_bounds__(256) void tail_kernel(
    const float* __restrict__ ctx, const float* __restrict__ S,
    const float* __restrict__ Wo, const float* __restrict__ bo,
    const float* __restrict__ g0, const float* __restrict__ beta0,
    const float* __restrict__ W1, const float* __restrict__ b1,
    const float* __restrict__ W2, const float* __restrict__ b2,
    const float* __restrict__ g1, const float* __restrict__ beta1,
    float* __restrict__ out)
{
    __shared__ float xin[8][NH];
    __shared__ float x1[8][NH];
    __shared__ float ybuf[8][NFF];
    const int t = threadIdx.x;
    const int row0 = blockIdx.x * 8;

    #pragma unroll
    for (int r = 0; r < 8; ++r) xin[r][t] = ctx[(size_t)(row0 + r) * NH + t];
    __syncthreads();

    // GEMM1: ctx @ Wo
    float acc[8];
    #pragma unroll
    for (int r = 0; r < 8; ++r) acc[r] = 0.0f;
    for (int e = 0; e < NH; e += 4) {
        const float w0 = Wo[(size_t)(e + 0) * NH + t];
        const float w1 = Wo[(size_t)(e + 1) * NH + t];
        const float w2 = Wo[(size_t)(e + 2) * NH + t];
        const float w3 = Wo[(size_t)(e + 3) * NH + t];
        #pragma unroll
        for (int r = 0; r < 8; ++r) {
            const float4 x4 = *(const float4*)&xin[r][e];
            acc[r] = fmaf(x4.x, w0, fmaf(x4.y, w1, fmaf(x4.z, w2, fmaf(x4.w, w3, acc[r]))));
        }
    }
    const float boc = bo[t];
    #pragma unroll
    for (int r = 0; r < 8; ++r) {
        const float xv = fmaxf(acc[r] + boc, 0.0f);
        x1[r][t] = S[(size_t)(row0 + r) * NH + t] + xv;
    }
    __syncthreads();

    // LN0 (in place on x1)
    {
        const int wv = t >> 6, ln = t & 63;
        #pragma unroll
        for (int rr = 0; rr < 2; ++rr) {
            const int r = wv * 2 + rr;
            float s1 = 0.0f, s2 = 0.0f;
            #pragma unroll
            for (int k = 0; k < 4; ++k) {
                const float z = x1[r][ln + 64 * k];
                s1 += z; s2 += z * z;
            }
            #pragma unroll
            for (int off = 32; off >= 1; off >>= 1) {
                s1 += __shfl_xor(s1, off);
                s2 += __shfl_xor(s2, off);
            }
            const float mu = s1 * (1.0f / NH);
            const float rsig = rsqrtf(s2 * (1.0f / NH) - mu * mu + LNEPS);
            #pragma unroll
            for (int k = 0; k < 4; ++k) {
                const int c = ln + 64 * k;
                x1[r][c] = (x1[r][c] - mu) * rsig * g0[c] + beta0[c];
            }
        }
    }
    __syncthreads();

    // GEMM2: x1 @ W1 (+b1, relu) -> ybuf
    float acc2[8][4];
    #pragma unroll
    for (int r = 0; r < 8; ++r)
        #pragma unroll
        for (int q = 0; q < 4; ++q) acc2[r][q] = 0.0f;
    for (int e = 0; e < NH; e += 4) {
        float4 x4[8];
        #pragma unroll
        for (int r = 0; r < 8; ++r) x4[r] = *(const float4*)&x1[r][e];
        #pragma unroll
        for (int q = 0; q < 4; ++q) {
            const float* wc = W1 + (size_t)e * NFF + (t + 256 * q);
            const float w0 = wc[0 * NFF], w1 = wc[1 * NFF], w2 = wc[2 * NFF], w3 = wc[3 * NFF];
            #pragma unroll
            for (int r = 0; r < 8; ++r)
                acc2[r][q] = fmaf(x4[r].x, w0, fmaf(x4[r].y, w1, fmaf(x4[r].z, w2, fmaf(x4[r].w, w3, acc2[r][q]))));
        }
    }
    #pragma unroll
    for (int q = 0; q < 4; ++q) {
        const float b1c = b1[t + 256 * q];
        #pragma unroll
        for (int r = 0; r < 8; ++r)
            ybuf[r][t + 256 * q] = fmaxf(acc2[r][q] + b1c, 0.0f);
    }
    __syncthreads();

    // GEMM3: ybuf @ W2 (+b2) + x1 residual
    float acc3[8];
    #pragma unroll
    for (int r = 0; r < 8; ++r) acc3[r] = 0.0f;
    for (int f = 0; f < NFF; f += 4) {
        const float w0 = W2[(size_t)(f + 0) * NH + t];
        const float w1 = W2[(size_t)(f + 1) * NH + t];
        const float w2 = W2[(size_t)(f + 2) * NH + t];
        const float w3 = W2[(size_t)(f + 3) * NH + t];
        #pragma unroll
        for (int r = 0; r < 8; ++r) {
            const float4 y4 = *(const float4*)&ybuf[r][f];
            acc3[r] = fmaf(y4.x, w0, fmaf(y4.y, w1, fmaf(y4.z, w2, fmaf(y4.w, w3, acc3[r]))));
        }
    }
    const float b2c = b2[t];
    #pragma unroll
    for (int r = 0; r < 8; ++r)
        xin[r][t] = x1[r][t] + acc3[r] + b2c;
    __syncthreads();

    // LN1 -> out (NT stores)
    {
        const int wv = t >> 6, ln = t & 63;
        #pragma unroll
        for (int rr = 0; rr < 2; ++rr) {
            const int r = wv * 2 + rr;
            float s1 = 0.0f, s2 = 0.0f;
            #pragma unroll
            for (int k = 0; k < 4; ++k) {
                const float z = xin[r][ln + 64 * k];
                s1 += z; s2 += z * z;
            }
            #pragma unroll
            for (int off = 32; off >= 1; off >>= 1) {
                s1 += __shfl_xor(s1, off);
                s2 += __shfl_xor(s2, off);
            }
            const float mu = s1 * (1.0f / NH);
            const float rsig = rsqrtf(s2 * (1.0f / NH) - mu * mu + LNEPS);
            #pragma unroll
            for (int k = 0; k < 4; ++k) {
                const int c = ln + 64 * k;
                const float o = (xin[r][c] - mu) * rsig * g1[c] + beta1[c];
                __builtin_nontemporal_store(o, &out[(size_t)(row0 + r) * NH + c]);
            }
        }
    }
}

// ---------------------------------------------------------------------------
extern "C" void kernel_launch(void* const* d_in, const int* in_sizes, int n_in,
                              void* d_out, int out_size, void* d_ws, size_t ws_size,
                              hipStream_t stream) {
    const float* S     = (const float*)d_in[0];
    const float* T     = (const float*)d_in[1];
    const int*   masks = (const int*)  d_in[2];
    const float* Wqk   = (const float*)d_in[3];
    const float* Wv    = (const float*)d_in[4];
    const float* bv    = (const float*)d_in[5];
    const float* Wo    = (const float*)d_in[6];
    const float* bo    = (const float*)d_in[7];
    const float* g0    = (const float*)d_in[8];
    const float* beta0 = (const float*)d_in[9];
    const float* W1    = (const float*)d_in[10];
    const float* b1    = (const float*)d_in[11];
    const float* W2    = (const float*)d_in[12];
    const float* b2    = (const float*)d_in[13];
    const float* g1    = (const float*)d_in[14];
    const float* beta1 = (const float*)d_in[15];

    float* out      = (float*)d_out;
    float* attn_out = out + (size_t)NB * NN * NH;   // scores, then attn in place
    float* v_ws     = (float*)d_ws;                 // 2 MB
    short8* wqk_bf  = (short8*)((char*)d_ws + (size_t)NB * NHEADS * NN * NSUBH * 4);
    float* ctx      = out;                          // reuse out region as scratch

    vproj_kernel<<<NB * NN / 8 + 1, 256, 0, stream>>>(S, Wv, bv, v_ws, Wqk, wqk_bf);
    scores_kernel<<<NB * NN * 8, 256, 0, stream>>>(T, wqk_bf, attn_out);
    softmax_ctx_kernel<<<NB * NN, 256, 0, stream>>>(masks, v_ws, attn_out, ctx);
    tail_kernel<<<NB * NN / 8, 256, 0, stream>>>(ctx, S, Wo, bo, g0, beta0,
                                                 W1, b1, W2, b2, g1, beta1, out);
}

// Round 12
// 340.584 us; speedup vs baseline: 1.1825x; 1.1825x over previous
//
#include <hip/hip_runtime.h>
#include <hip/hip_bf16.h>
#include <cstddef>

#define NB 4
#define NN 512
#define NH 256
#define NHEADS 8
#define NSUBH 32
#define NFF 1024
#define LNEPS 1e-5f

using short8 = __attribute__((ext_vector_type(8))) short;
using f32x4  = __attribute__((ext_vector_type(4))) float;
using fvec4  = __attribute__((ext_vector_type(4))) float;

__device__ __forceinline__ unsigned short f2bf(float x) {
    __hip_bfloat16 h = __float2bfloat16(x);          // HW RNE cvt
    return *reinterpret_cast<unsigned short*>(&h);
}

// ---------------------------------------------------------------------------
// Kernel P: pack Wqk into bf16 MFMA B-fragment order.
// ---------------------------------------------------------------------------
__global__ __launch_bounds__(64) void prep_wqk_kernel(
    const float* __restrict__ Wqk, short8* __restrict__ wqk_bf)
{
    const int lane = threadIdx.x;
    const int n = lane & 15;
    #pragma unroll
    for (int ks = 0; ks < 8; ++ks) {
        short8 v;
        #pragma unroll
        for (int q = 0; q < 8; ++q) {
            const int k = ks * 32 + ((lane >> 4) & 3) * 8 + q;
            v[q] = (n < 8) ? (short)f2bf(Wqk[k * NHEADS + n]) : (short)0;
        }
        wqk_bf[ks * 64 + lane] = v;
    }
}

// ---------------------------------------------------------------------------
// Kernel A: V projection. v[b,h,j,d] = S[b,j,:]·Wv[:,h*32+d] + bv[h*32+d]
// ---------------------------------------------------------------------------
__global__ __launch_bounds__(256) void vproj_kernel(
    const float* __restrict__ S, const float* __restrict__ Wv,
    const float* __restrict__ bv, float* __restrict__ v_ws)
{
    __shared__ float srow[8][NH];
    const int t = threadIdx.x;
    const int row0 = blockIdx.x * 8;
    #pragma unroll
    for (int r = 0; r < 8; ++r) srow[r][t] = S[(size_t)(row0 + r) * NH + t];
    __syncthreads();

    float acc[8];
    #pragma unroll
    for (int r = 0; r < 8; ++r) acc[r] = 0.0f;
    for (int e = 0; e < NH; e += 4) {
        const float w0 = Wv[(size_t)(e + 0) * NH + t];
        const float w1 = Wv[(size_t)(e + 1) * NH + t];
        const float w2 = Wv[(size_t)(e + 2) * NH + t];
        const float w3 = Wv[(size_t)(e + 3) * NH + t];
        #pragma unroll
        for (int r = 0; r < 8; ++r) {
            const float4 x4 = *(const float4*)&srow[r][e];
            acc[r] = fmaf(x4.x, w0, fmaf(x4.y, w1, fmaf(x4.z, w2, fmaf(x4.w, w3, acc[r]))));
        }
    }
    const float bvc = bv[t];
    const int h = t >> 5, d = t & 31;
    const int b = row0 / NN;
    const int jbase = row0 & (NN - 1);
    #pragma unroll
    for (int r = 0; r < 8; ++r)
        v_ws[((size_t)(b * NHEADS + h) * NN + (size_t)(jbase + r)) * NSUBH + d] = acc[r] + bvc;
}

// ---------------------------------------------------------------------------
// Kernel B1: raw attention scores via MFMA — wave-autonomous, NT loads.
// Block = 64 j-rows of one (b,i); wave wv owns rows 16wv..16wv+15.
// T loads are NON-TEMPORAL (zero-reuse 1.07GB stream; bypass L2/L3
// allocation). Wave-private LDS slice, XOR-swizzled, zero __syncthreads.
// ---------------------------------------------------------------------------
__global__ __launch_bounds__(256, 4) void scores_kernel(
    const float* __restrict__ T, const short8* __restrict__ wqk_bf,
    float* __restrict__ scores)
{
    __shared__ unsigned short tlds[64 * 256];   // 32 KB bf16 T-tile
    const int t = threadIdx.x;
    const int lane = t & 63, wv = t >> 6;
    const int bi = blockIdx.x >> 3;             // b*512 + i
    const int jt = blockIdx.x & 7;
    const int jbase = jt * 64;

    const fvec4* Tv = (const fvec4*)(T + ((size_t)bi * NN + jbase) * NH);

    // 1. issue 16 dense row-loads, non-temporal (1KB contiguous per instr)
    fvec4 ga[16];
    #pragma unroll
    for (int i = 0; i < 16; ++i)
        ga[i] = __builtin_nontemporal_load(&Tv[(size_t)(16 * wv + i) * 64 + lane]);

    // 2. B-fragments from pre-packed global (L2-hot) while T-loads fly
    short8 bfrag[8];
    #pragma unroll
    for (int ks = 0; ks < 8; ++ks) bfrag[ks] = wqk_bf[ks * 64 + lane];

    // 3. convert + stage wave-private rows (uniform row per instr, 512B dense)
    #pragma unroll
    for (int i = 0; i < 16; ++i) {
        const int row = 16 * wv + i;
        unsigned short v[4];
        v[0] = f2bf(ga[i][0]); v[1] = f2bf(ga[i][1]);
        v[2] = f2bf(ga[i][2]); v[3] = f2bf(ga[i][3]);
        const int byte = (row * 512 + lane * 8) ^ ((row & 7) << 4);
        *(uint2*)((char*)tlds + byte) = *(const uint2*)v;
    }

    // 4. K-loop: 8 x mfma 16x16x32 on own rows (lgkmcnt ordering, no barrier)
    f32x4 acc = {0.0f, 0.0f, 0.0f, 0.0f};
    const int jr = 16 * wv + (lane & 15);
    #pragma unroll
    for (int ks = 0; ks < 8; ++ks) {
        const int byte = (jr * 512 + ks * 64 + (lane >> 4) * 16) ^ ((jr & 7) << 4);
        const short8 af = *(const short8*)((const char*)tlds + byte);
        acc = __builtin_amdgcn_mfma_f32_16x16x32_bf16(af, bfrag[ks], acc, 0, 0, 0);
    }

    // 5. store raw scores: lane holds col h=lane&15 (<8 valid), 4 j-rows
    const int h = lane & 15;
    if (h < 8) {
        const int b = bi >> 9, i = bi & (NN - 1);
        const int j0 = jbase + 16 * wv + (lane >> 4) * 4;
        float4 st;
        st.x = acc[0]; st.y = acc[1]; st.z = acc[2]; st.w = acc[3];
        *(float4*)&scores[((size_t)(b * NHEADS + h) * NN + i) * NN + j0] = st;
    }
}

// ---------------------------------------------------------------------------
// Kernel B2: softmax (+mask) over raw scores -> attn (in place) + ctx.
// ---------------------------------------------------------------------------
__global__ __launch_bounds__(256) void softmax_ctx_kernel(
    const int* __restrict__ masks, const float* __restrict__ v_ws,
    float* __restrict__ attn, float* __restrict__ ctx_out)
{
    __shared__ float sc[NN][9];
    __shared__ float maddv[NN];
    const int t = threadIdx.x;
    const int b = blockIdx.x >> 9;
    const int i = blockIdx.x & (NN - 1);

    const int mi = masks[b * NN + i];
    for (int j = t; j < NN; j += 256)
        maddv[j] = (mi != 0 && masks[b * NN + j] != 0) ? 0.0f : -1000.0f;
    __syncthreads();

    const int h = t >> 5;
    const int l32 = t & 31;
    float* srow = attn + ((size_t)(b * NHEADS + h) * NN + i) * NN;

    float vals[16];
    float m = -1e30f;
    #pragma unroll
    for (int k = 0; k < 4; ++k) {
        const int j0 = 4 * l32 + 128 * k;
        float4 s4 = *(const float4*)&srow[j0];
        const float4 m4 = *(const float4*)&maddv[j0];
        s4.x += m4.x; s4.y += m4.y; s4.z += m4.z; s4.w += m4.w;
        vals[4 * k + 0] = s4.x; vals[4 * k + 1] = s4.y;
        vals[4 * k + 2] = s4.z; vals[4 * k + 3] = s4.w;
        m = fmaxf(m, fmaxf(fmaxf(s4.x, s4.y), fmaxf(s4.z, s4.w)));
    }
    #pragma unroll
    for (int off = 16; off >= 1; off >>= 1) m = fmaxf(m, __shfl_xor(m, off, 32));
    float sum = 0.0f;
    #pragma unroll
    for (int k = 0; k < 16; ++k) {
        const float e = __expf(vals[k] - m);
        vals[k] = e;
        sum += e;
    }
    #pragma unroll
    for (int off = 16; off >= 1; off >>= 1) sum += __shfl_xor(sum, off, 32);
    const float inv = 1.0f / sum;
    #pragma unroll
    for (int k = 0; k < 4; ++k) {
        const int j0 = 4 * l32 + 128 * k;
        float4 p4;
        p4.x = vals[4 * k + 0] * inv; p4.y = vals[4 * k + 1] * inv;
        p4.z = vals[4 * k + 2] * inv; p4.w = vals[4 * k + 3] * inv;
        *(float4*)&srow[j0] = p4;
        sc[j0 + 0][h] = p4.x; sc[j0 + 1][h] = p4.y;
        sc[j0 + 2][h] = p4.z; sc[j0 + 3][h] = p4.w;
    }
    __syncthreads();

    // ctx[h][d] = sum_j P[h][j] * v[b,h,j,d]
    const int d = l32;
    const float* vp = v_ws + (size_t)(b * NHEADS + h) * NN * NSUBH + d;
    float acc = 0.0f;
    #pragma unroll 8
    for (int j = 0; j < NN; ++j)
        acc = fmaf(sc[j][h], vp[(size_t)j * NSUBH], acc);
    ctx_out[(size_t)(b * NN + i) * NH + h * NSUBH + d] = acc;
}

// ---------------------------------------------------------------------------
// Kernel C: tail. x=relu(ctx·Wo+bo); x1=LN(S+x); y=relu(x1·W1+b1)·W2+b2;
// out=LN(x1+y). 8 rows per block, 256 blocks, 256 threads.
// ---------------------------------------------------------------------------
__global__ __launch_bounds__(256) void tail_kernel(
    const float* __restrict__ ctx, const float* __restrict__ S,
    const float* __restrict__ Wo, const float* __restrict__ bo,
    const float* __restrict__ g0, const float* __restrict__ beta0,
    const float* __restrict__ W1, const float* __restrict__ b1,
    const float* __restrict__ W2, const float* __restrict__ b2,
    const float* __restrict__ g1, const float* __restrict__ beta1,
    float* __restrict__ out)
{
    __shared__ float xin[8][NH];
    __shared__ float x1[8][NH];
    __shared__ float ybuf[8][NFF];
    const int t = threadIdx.x;
    const int row0 = blockIdx.x * 8;

    #pragma unroll
    for (int r = 0; r < 8; ++r) xin[r][t] = ctx[(size_t)(row0 + r) * NH + t];
    __syncthreads();

    // GEMM1: ctx @ Wo
    float acc[8];
    #pragma unroll
    for (int r = 0; r < 8; ++r) acc[r] = 0.0f;
    for (int e = 0; e < NH; e += 4) {
        const float w0 = Wo[(size_t)(e + 0) * NH + t];
        const float w1 = Wo[(size_t)(e + 1) * NH + t];
        const float w2 = Wo[(size_t)(e + 2) * NH + t];
        const float w3 = Wo[(size_t)(e + 3) * NH + t];
        #pragma unroll
        for (int r = 0; r < 8; ++r) {
            const float4 x4 = *(const float4*)&xin[r][e];
            acc[r] = fmaf(x4.x, w0, fmaf(x4.y, w1, fmaf(x4.z, w2, fmaf(x4.w, w3, acc[r]))));
        }
    }
    const float boc = bo[t];
    #pragma unroll
    for (int r = 0; r < 8; ++r) {
        const float xv = fmaxf(acc[r] + boc, 0.0f);
        x1[r][t] = S[(size_t)(row0 + r) * NH + t] + xv;
    }
    __syncthreads();

    // LN0 (in place on x1)
    {
        const int wv = t >> 6, ln = t & 63;
        #pragma unroll
        for (int rr = 0; rr < 2; ++rr) {
            const int r = wv * 2 + rr;
            float s1 = 0.0f, s2 = 0.0f;
            #pragma unroll
            for (int k = 0; k < 4; ++k) {
                const float z = x1[r][ln + 64 * k];
                s1 += z; s2 += z * z;
            }
            #pragma unroll
            for (int off = 32; off >= 1; off >>= 1) {
                s1 += __shfl_xor(s1, off);
                s2 += __shfl_xor(s2, off);
            }
            const float mu = s1 * (1.0f / NH);
            const float rsig = rsqrtf(s2 * (1.0f / NH) - mu * mu + LNEPS);
            #pragma unroll
            for (int k = 0; k < 4; ++k) {
                const int c = ln + 64 * k;
                x1[r][c] = (x1[r][c] - mu) * rsig * g0[c] + beta0[c];
            }
        }
    }
    __syncthreads();

    // GEMM2: x1 @ W1 (+b1, relu) -> ybuf
    float acc2[8][4];
    #pragma unroll
    for (int r = 0; r < 8; ++r)
        #pragma unroll
        for (int q = 0; q < 4; ++q) acc2[r][q] = 0.0f;
    for (int e = 0; e < NH; e += 4) {
        float4 x4[8];
        #pragma unroll
        for (int r = 0; r < 8; ++r) x4[r] = *(const float4*)&x1[r][e];
        #pragma unroll
        for (int q = 0; q < 4; ++q) {
            const float* wc = W1 + (size_t)e * NFF + (t + 256 * q);
            const float w0 = wc[0 * NFF], w1 = wc[1 * NFF], w2 = wc[2 * NFF], w3 = wc[3 * NFF];
            #pragma unroll
            for (int r = 0; r < 8; ++r)
                acc2[r][q] = fmaf(x4[r].x, w0, fmaf(x4[r].y, w1, fmaf(x4[r].z, w2, fmaf(x4[r].w, w3, acc2[r][q]))));
        }
    }
    #pragma unroll
    for (int q = 0; q < 4; ++q) {
        const float b1c = b1[t + 256 * q];
        #pragma unroll
        for (int r = 0; r < 8; ++r)
            ybuf[r][t + 256 * q] = fmaxf(acc2[r][q] + b1c, 0.0f);
    }
    __syncthreads();

    // GEMM3: ybuf @ W2 (+b2) + x1 residual
    float acc3[8];
    #pragma unroll
    for (int r = 0; r < 8; ++r) acc3[r] = 0.0f;
    for (int f = 0; f < NFF; f += 4) {
        const float w0 = W2[(size_t)(f + 0) * NH + t];
        const float w1 = W2[(size_t)(f + 1) * NH + t];
        const float w2 = W2[(size_t)(f + 2) * NH + t];
        const float w3 = W2[(size_t)(f + 3) * NH + t];
        #pragma unroll
        for (int r = 0; r < 8; ++r) {
            const float4 y4 = *(const float4*)&ybuf[r][f];
            acc3[r] = fmaf(y4.x, w0, fmaf(y4.y, w1, fmaf(y4.z, w2, fmaf(y4.w, w3, acc3[r]))));
        }
    }
    const float b2c = b2[t];
    #pragma unroll
    for (int r = 0; r < 8; ++r)
        xin[r][t] = x1[r][t] + acc3[r] + b2c;
    __syncthreads();

    // LN1 -> out
    {
        const int wv = t >> 6, ln = t & 63;
        #pragma unroll
        for (int rr = 0; rr < 2; ++rr) {
            const int r = wv * 2 + rr;
            float s1 = 0.0f, s2 = 0.0f;
            #pragma unroll
            for (int k = 0; k < 4; ++k) {
                const float z = xin[r][ln + 64 * k];
                s1 += z; s2 += z * z;
            }
            #pragma unroll
            for (int off = 32; off >= 1; off >>= 1) {
                s1 += __shfl_xor(s1, off);
                s2 += __shfl_xor(s2, off);
            }
            const float mu = s1 * (1.0f / NH);
            const float rsig = rsqrtf(s2 * (1.0f / NH) - mu * mu + LNEPS);
            #pragma unroll
            for (int k = 0; k < 4; ++k) {
                const int c = ln + 64 * k;
                out[(size_t)(row0 + r) * NH + c] = (xin[r][c] - mu) * rsig * g1[c] + beta1[c];
            }
        }
    }
}

// ---------------------------------------------------------------------------
extern "C" void kernel_launch(void* const* d_in, const int* in_sizes, int n_in,
                              void* d_out, int out_size, void* d_ws, size_t ws_size,
                              hipStream_t stream) {
    const float* S     = (const float*)d_in[0];
    const float* T     = (const float*)d_in[1];
    const int*   masks = (const int*)  d_in[2];
    const float* Wqk   = (const float*)d_in[3];
    const float* Wv    = (const float*)d_in[4];
    const float* bv    = (const float*)d_in[5];
    const float* Wo    = (const float*)d_in[6];
    const float* bo    = (const float*)d_in[7];
    const float* g0    = (const float*)d_in[8];
    const float* beta0 = (const float*)d_in[9];
    const float* W1    = (const float*)d_in[10];
    const float* b1    = (const float*)d_in[11];
    const float* W2    = (const float*)d_in[12];
    const float* b2    = (const float*)d_in[13];
    const float* g1    = (const float*)d_in[14];
    const float* beta1 = (const float*)d_in[15];

    float* out      = (float*)d_out;
    float* attn_out = out + (size_t)NB * NN * NH;   // scores, then attn in place
    float* v_ws     = (float*)d_ws;                 // 2 MB
    short8* wqk_bf  = (short8*)((char*)d_ws + (size_t)NB * NHEADS * NN * NSUBH * 4);
    float* ctx      = out;                          // reuse out region as scratch

    prep_wqk_kernel<<<1, 64, 0, stream>>>(Wqk, wqk_bf);
    vproj_kernel<<<NB * NN / 8, 256, 0, stream>>>(S, Wv, bv, v_ws);
    scores_kernel<<<NB * NN * 8, 256, 0, stream>>>(T, wqk_bf, attn_out);
    softmax_ctx_kernel<<<NB * NN, 256, 0, stream>>>(masks, v_ws, attn_out, ctx);
    tail_kernel<<<NB * NN / 8, 256, 0, stream>>>(ctx, S, Wo, bo, g0, beta0,
                                                 W1, b1, W2, b2, g1, beta1, out);
}

// Round 13
// 326.817 us; speedup vs baseline: 1.2323x; 1.0421x over previous
//
#include <hip/hip_runtime.h>
#include <hip/hip_bf16.h>
#include <cstddef>

#define NB 4
#define NN 512
#define NH 256
#define NHEADS 8
#define NSUBH 32
#define NFF 1024
#define LNEPS 1e-5f

using short8 = __attribute__((ext_vector_type(8))) short;
using f32x4  = __attribute__((ext_vector_type(4))) float;
using fvec4  = __attribute__((ext_vector_type(4))) float;

__device__ __forceinline__ unsigned short f2bf(float x) {
    __hip_bfloat16 h = __float2bfloat16(x);          // HW RNE cvt
    return *reinterpret_cast<unsigned short*>(&h);
}

// ---------------------------------------------------------------------------
// Kernel P: pack Wqk into bf16 MFMA B-fragment order.
// ---------------------------------------------------------------------------
__global__ __launch_bounds__(64) void prep_wqk_kernel(
    const float* __restrict__ Wqk, short8* __restrict__ wqk_bf)
{
    const int lane = threadIdx.x;
    const int n = lane & 15;
    #pragma unroll
    for (int ks = 0; ks < 8; ++ks) {
        short8 v;
        #pragma unroll
        for (int q = 0; q < 8; ++q) {
            const int k = ks * 32 + ((lane >> 4) & 3) * 8 + q;
            v[q] = (n < 8) ? (short)f2bf(Wqk[k * NHEADS + n]) : (short)0;
        }
        wqk_bf[ks * 64 + lane] = v;
    }
}

// ---------------------------------------------------------------------------
// Kernel A: V projection. v[b,h,j,d] = S[b,j,:]·Wv[:,h*32+d] + bv[h*32+d]
// ---------------------------------------------------------------------------
__global__ __launch_bounds__(256) void vproj_kernel(
    const float* __restrict__ S, const float* __restrict__ Wv,
    const float* __restrict__ bv, float* __restrict__ v_ws)
{
    __shared__ float srow[8][NH];
    const int t = threadIdx.x;
    const int row0 = blockIdx.x * 8;
    #pragma unroll
    for (int r = 0; r < 8; ++r) srow[r][t] = S[(size_t)(row0 + r) * NH + t];
    __syncthreads();

    float acc[8];
    #pragma unroll
    for (int r = 0; r < 8; ++r) acc[r] = 0.0f;
    for (int e = 0; e < NH; e += 4) {
        const float w0 = Wv[(size_t)(e + 0) * NH + t];
        const float w1 = Wv[(size_t)(e + 1) * NH + t];
        const float w2 = Wv[(size_t)(e + 2) * NH + t];
        const float w3 = Wv[(size_t)(e + 3) * NH + t];
        #pragma unroll
        for (int r = 0; r < 8; ++r) {
            const float4 x4 = *(const float4*)&srow[r][e];
            acc[r] = fmaf(x4.x, w0, fmaf(x4.y, w1, fmaf(x4.z, w2, fmaf(x4.w, w3, acc[r]))));
        }
    }
    const float bvc = bv[t];
    const int h = t >> 5, d = t & 31;
    const int b = row0 / NN;
    const int jbase = row0 & (NN - 1);
    #pragma unroll
    for (int r = 0; r < 8; ++r)
        v_ws[((size_t)(b * NHEADS + h) * NN + (size_t)(jbase + r)) * NSUBH + d] = acc[r] + bvc;
}

// ---------------------------------------------------------------------------
// Kernel B (FUSED): scores (MFMA, NT loads) + softmax + attn write + ctx.
// One block per (b,i), 256 thr = 4 waves. Wave wv streams j-rows
// [wv*128, wv*128+128) in 8 tiles of 16 through its PRIVATE LDS slice
// (round-9 inner pipeline: NT 1KB-row loads -> cvt -> swizzled slice ->
// 8x mfma). C-fragments go straight to LDS sc2[h][j] (float4, bank-uniform)
// -- NO global score round-trip. Then one barrier -> softmax from LDS ->
// attn global write + P back to sc2 -> barrier -> ctx.
// ---------------------------------------------------------------------------
__global__ __launch_bounds__(256, 3) void attn_fused_kernel(
    const float* __restrict__ T, const short8* __restrict__ wqk_bf,
    const int* __restrict__ masks, const float* __restrict__ v_ws,
    float* __restrict__ attn, float* __restrict__ ctx_out)
{
    __shared__ unsigned short tlds[4 * 16 * 256];   // 32 KB: 4 wave slices
    __shared__ float sc2[NHEADS][516];              // 16.5 KB scores/P
    __shared__ float maddv[NN];                     // 2 KB
    const int t = threadIdx.x;
    const int lane = t & 63, wv = t >> 6;
    const int bi = blockIdx.x;
    const int b = bi >> 9, i = bi & (NN - 1);

    const int mi = masks[b * NN + i];
    for (int j = t; j < NN; j += 256)
        maddv[j] = (mi != 0 && masks[b * NN + j] != 0) ? 0.0f : -1000.0f;

    // B-fragments from pre-packed global (L2-hot)
    short8 bfrag[8];
    #pragma unroll
    for (int ks = 0; ks < 8; ++ks) bfrag[ks] = wqk_bf[ks * 64 + lane];

    const fvec4* Tv = (const fvec4*)(T + (size_t)bi * NN * NH);
    char* slice = (char*)tlds + wv * 8192;          // wave-private 16-row slice
    const int h = lane & 15;
    const int jrl = lane & 15;

    for (int tile = 0; tile < 8; ++tile) {
        const int jb = wv * 128 + tile * 16;
        // 1. 16 dense NT row-loads (1KB contiguous per wave-instr)
        fvec4 ga[16];
        #pragma unroll
        for (int r = 0; r < 16; ++r)
            ga[r] = __builtin_nontemporal_load(&Tv[(size_t)(jb + r) * 64 + lane]);
        // 2. cvt + stage into wave slice (uniform row per instr, swizzled)
        #pragma unroll
        for (int r = 0; r < 16; ++r) {
            unsigned short v[4];
            v[0] = f2bf(ga[r][0]); v[1] = f2bf(ga[r][1]);
            v[2] = f2bf(ga[r][2]); v[3] = f2bf(ga[r][3]);
            const int byte = (r * 512 + lane * 8) ^ ((r & 7) << 4);
            *(uint2*)(slice + byte) = *(const uint2*)v;
        }
        // 3. 8x mfma 16x16x32 (intra-wave ds ordering, no barrier)
        f32x4 acc = {0.0f, 0.0f, 0.0f, 0.0f};
        #pragma unroll
        for (int ks = 0; ks < 8; ++ks) {
            const int byte = (jrl * 512 + ks * 64 + (lane >> 4) * 16) ^ ((jrl & 7) << 4);
            const short8 af = *(const short8*)(slice + byte);
            acc = __builtin_amdgcn_mfma_f32_16x16x32_bf16(af, bfrag[ks], acc, 0, 0, 0);
        }
        // 4. C-frag -> LDS scores: lane holds col h (<8 valid), rows j0..j0+3
        if (h < 8) {
            const int j0 = jb + (lane >> 4) * 4;
            *(float4*)&sc2[h][j0] = make_float4(acc[0], acc[1], acc[2], acc[3]);
        }
    }
    __syncthreads();

    // -------- softmax per head (32 threads/head), from LDS --------
    const int sh = t >> 5;
    const int l32 = t & 31;
    float* arow = attn + ((size_t)(b * NHEADS + sh) * NN + i) * NN;

    float vals[16];
    float m = -1e30f;
    #pragma unroll
    for (int k = 0; k < 4; ++k) {
        const int j0 = 4 * l32 + 128 * k;
        float4 s4 = *(const float4*)&sc2[sh][j0];
        const float4 m4 = *(const float4*)&maddv[j0];
        s4.x += m4.x; s4.y += m4.y; s4.z += m4.z; s4.w += m4.w;
        vals[4 * k + 0] = s4.x; vals[4 * k + 1] = s4.y;
        vals[4 * k + 2] = s4.z; vals[4 * k + 3] = s4.w;
        m = fmaxf(m, fmaxf(fmaxf(s4.x, s4.y), fmaxf(s4.z, s4.w)));
    }
    #pragma unroll
    for (int off = 16; off >= 1; off >>= 1) m = fmaxf(m, __shfl_xor(m, off, 32));
    float sum = 0.0f;
    #pragma unroll
    for (int k = 0; k < 16; ++k) {
        const float e = __expf(vals[k] - m);
        vals[k] = e;
        sum += e;
    }
    #pragma unroll
    for (int off = 16; off >= 1; off >>= 1) sum += __shfl_xor(sum, off, 32);
    const float inv = 1.0f / sum;
    #pragma unroll
    for (int k = 0; k < 4; ++k) {
        const int j0 = 4 * l32 + 128 * k;
        float4 p4;
        p4.x = vals[4 * k + 0] * inv; p4.y = vals[4 * k + 1] * inv;
        p4.z = vals[4 * k + 2] * inv; p4.w = vals[4 * k + 3] * inv;
        *(float4*)&arow[j0] = p4;
        *(float4*)&sc2[sh][j0] = p4;
    }
    __syncthreads();

    // -------- ctx[h][d] = sum_j P[h][j] * v[b,h,j,d] --------
    const int d = l32;
    const float* vp = v_ws + (size_t)(b * NHEADS + sh) * NN * NSUBH + d;
    float acc = 0.0f;
    #pragma unroll 8
    for (int j = 0; j < NN; ++j)
        acc = fmaf(sc2[sh][j], vp[(size_t)j * NSUBH], acc);
    ctx_out[(size_t)(b * NN + i) * NH + sh * NSUBH + d] = acc;
}

// ---------------------------------------------------------------------------
// Kernel C: tail. x=relu(ctx·Wo+bo); x1=LN(S+x); y=relu(x1·W1+b1)·W2+b2;
// out=LN(x1+y). 8 rows per block, 256 blocks, 256 threads.
// ---------------------------------------------------------------------------
__global__ __launch_bounds__(256) void tail_kernel(
    const float* __restrict__ ctx, const float* __restrict__ S,
    const float* __restrict__ Wo, const float* __restrict__ bo,
    const float* __restrict__ g0, const float* __restrict__ beta0,
    const float* __restrict__ W1, const float* __restrict__ b1,
    const float* __restrict__ W2, const float* __restrict__ b2,
    const float* __restrict__ g1, const float* __restrict__ beta1,
    float* __restrict__ out)
{
    __shared__ float xin[8][NH];
    __shared__ float x1[8][NH];
    __shared__ float ybuf[8][NFF];
    const int t = threadIdx.x;
    const int row0 = blockIdx.x * 8;

    #pragma unroll
    for (int r = 0; r < 8; ++r) xin[r][t] = ctx[(size_t)(row0 + r) * NH + t];
    __syncthreads();

    // GEMM1: ctx @ Wo
    float acc[8];
    #pragma unroll
    for (int r = 0; r < 8; ++r) acc[r] = 0.0f;
    for (int e = 0; e < NH; e += 4) {
        const float w0 = Wo[(size_t)(e + 0) * NH + t];
        const float w1 = Wo[(size_t)(e + 1) * NH + t];
        const float w2 = Wo[(size_t)(e + 2) * NH + t];
        const float w3 = Wo[(size_t)(e + 3) * NH + t];
        #pragma unroll
        for (int r = 0; r < 8; ++r) {
            const float4 x4 = *(const float4*)&xin[r][e];
            acc[r] = fmaf(x4.x, w0, fmaf(x4.y, w1, fmaf(x4.z, w2, fmaf(x4.w, w3, acc[r]))));
        }
    }
    const float boc = bo[t];
    #pragma unroll
    for (int r = 0; r < 8; ++r) {
        const float xv = fmaxf(acc[r] + boc, 0.0f);
        x1[r][t] = S[(size_t)(row0 + r) * NH + t] + xv;
    }
    __syncthreads();

    // LN0 (in place on x1)
    {
        const int wv = t >> 6, ln = t & 63;
        #pragma unroll
        for (int rr = 0; rr < 2; ++rr) {
            const int r = wv * 2 + rr;
            float s1 = 0.0f, s2 = 0.0f;
            #pragma unroll
            for (int k = 0; k < 4; ++k) {
                const float z = x1[r][ln + 64 * k];
                s1 += z; s2 += z * z;
            }
            #pragma unroll
            for (int off = 32; off >= 1; off >>= 1) {
                s1 += __shfl_xor(s1, off);
                s2 += __shfl_xor(s2, off);
            }
            const float mu = s1 * (1.0f / NH);
            const float rsig = rsqrtf(s2 * (1.0f / NH) - mu * mu + LNEPS);
            #pragma unroll
            for (int k = 0; k < 4; ++k) {
                const int c = ln + 64 * k;
                x1[r][c] = (x1[r][c] - mu) * rsig * g0[c] + beta0[c];
            }
        }
    }
    __syncthreads();

    // GEMM2: x1 @ W1 (+b1, relu) -> ybuf
    float acc2[8][4];
    #pragma unroll
    for (int r = 0; r < 8; ++r)
        #pragma unroll
        for (int q = 0; q < 4; ++q) acc2[r][q] = 0.0f;
    for (int e = 0; e < NH; e += 4) {
        float4 x4[8];
        #pragma unroll
        for (int r = 0; r < 8; ++r) x4[r] = *(const float4*)&x1[r][e];
        #pragma unroll
        for (int q = 0; q < 4; ++q) {
            const float* wc = W1 + (size_t)e * NFF + (t + 256 * q);
            const float w0 = wc[0 * NFF], w1 = wc[1 * NFF], w2 = wc[2 * NFF], w3 = wc[3 * NFF];
            #pragma unroll
            for (int r = 0; r < 8; ++r)
                acc2[r][q] = fmaf(x4[r].x, w0, fmaf(x4[r].y, w1, fmaf(x4[r].z, w2, fmaf(x4[r].w, w3, acc2[r][q]))));
        }
    }
    #pragma unroll
    for (int q = 0; q < 4; ++q) {
        const float b1c = b1[t + 256 * q];
        #pragma unroll
        for (int r = 0; r < 8; ++r)
            ybuf[r][t + 256 * q] = fmaxf(acc2[r][q] + b1c, 0.0f);
    }
    __syncthreads();

    // GEMM3: ybuf @ W2 (+b2) + x1 residual
    float acc3[8];
    #pragma unroll
    for (int r = 0; r < 8; ++r) acc3[r] = 0.0f;
    for (int f = 0; f < NFF; f += 4) {
        const float w0 = W2[(size_t)(f + 0) * NH + t];
        const float w1 = W2[(size_t)(f + 1) * NH + t];
        const float w2 = W2[(size_t)(f + 2) * NH + t];
        const float w3 = W2[(size_t)(f + 3) * NH + t];
        #pragma unroll
        for (int r = 0; r < 8; ++r) {
            const float4 y4 = *(const float4*)&ybuf[r][f];
            acc3[r] = fmaf(y4.x, w0, fmaf(y4.y, w1, fmaf(y4.z, w2, fmaf(y4.w, w3, acc3[r]))));
        }
    }
    const float b2c = b2[t];
    #pragma unroll
    for (int r = 0; r < 8; ++r)
        xin[r][t] = x1[r][t] + acc3[r] + b2c;
    __syncthreads();

    // LN1 -> out
    {
        const int wv = t >> 6, ln = t & 63;
        #pragma unroll
        for (int rr = 0; rr < 2; ++rr) {
            const int r = wv * 2 + rr;
            float s1 = 0.0f, s2 = 0.0f;
            #pragma unroll
            for (int k = 0; k < 4; ++k) {
                const float z = xin[r][ln + 64 * k];
                s1 += z; s2 += z * z;
            }
            #pragma unroll
            for (int off = 32; off >= 1; off >>= 1) {
                s1 += __shfl_xor(s1, off);
                s2 += __shfl_xor(s2, off);
            }
            const float mu = s1 * (1.0f / NH);
            const float rsig = rsqrtf(s2 * (1.0f / NH) - mu * mu + LNEPS);
            #pragma unroll
            for (int k = 0; k < 4; ++k) {
                const int c = ln + 64 * k;
                out[(size_t)(row0 + r) * NH + c] = (xin[r][c] - mu) * rsig * g1[c] + beta1[c];
            }
        }
    }
}

// ---------------------------------------------------------------------------
extern "C" void kernel_launch(void* const* d_in, const int* in_sizes, int n_in,
                              void* d_out, int out_size, void* d_ws, size_t ws_size,
                              hipStream_t stream) {
    const float* S     = (const float*)d_in[0];
    const float* T     = (const float*)d_in[1];
    const int*   masks = (const int*)  d_in[2];
    const float* Wqk   = (const float*)d_in[3];
    const float* Wv    = (const float*)d_in[4];
    const float* bv    = (const float*)d_in[5];
    const float* Wo    = (const float*)d_in[6];
    const float* bo    = (const float*)d_in[7];
    const float* g0    = (const float*)d_in[8];
    const float* beta0 = (const float*)d_in[9];
    const float* W1    = (const float*)d_in[10];
    const float* b1    = (const float*)d_in[11];
    const float* W2    = (const float*)d_in[12];
    const float* b2    = (const float*)d_in[13];
    const float* g1    = (const float*)d_in[14];
    const float* beta1 = (const float*)d_in[15];

    float* out      = (float*)d_out;
    float* attn_out = out + (size_t)NB * NN * NH;   // attn region
    float* v_ws     = (float*)d_ws;                 // 2 MB
    short8* wqk_bf  = (short8*)((char*)d_ws + (size_t)NB * NHEADS * NN * NSUBH * 4);
    float* ctx      = out;                          // reuse out region as scratch

    prep_wqk_kernel<<<1, 64, 0, stream>>>(Wqk, wqk_bf);
    vproj_kernel<<<NB * NN / 8, 256, 0, stream>>>(S, Wv, bv, v_ws);
    attn_fused_kernel<<<NB * NN, 256, 0, stream>>>(T, wqk_bf, masks, v_ws,
                                                   attn_out, ctx);
    tail_kernel<<<NB * NN / 8, 256, 0, stream>>>(ctx, S, Wo, bo, g0, beta0,
                                                 W1, b1, W2, b2, g1, beta1, out);
}

// Round 14
// 318.472 us; speedup vs baseline: 1.2646x; 1.0262x over previous
//
#include <hip/hip_runtime.h>
#include <hip/hip_bf16.h>
#include <cstddef>

#define NB 4
#define NN 512
#define NH 256
#define NHEADS 8
#define NSUBH 32
#define NFF 1024
#define LNEPS 1e-5f

using short8 = __attribute__((ext_vector_type(8))) short;
using f32x4  = __attribute__((ext_vector_type(4))) float;
using fvec4  = __attribute__((ext_vector_type(4))) float;

__device__ __forceinline__ unsigned short f2bf(float x) {
    __hip_bfloat16 h = __float2bfloat16(x);          // HW RNE cvt
    return *reinterpret_cast<unsigned short*>(&h);
}

// ---------------------------------------------------------------------------
// Kernel A: V projection (blocks 0..255) + Wqk bf16 B-frag pack (block 256).
// ---------------------------------------------------------------------------
__global__ __launch_bounds__(256) void vproj_kernel(
    const float* __restrict__ S, const float* __restrict__ Wv,
    const float* __restrict__ bv, float* __restrict__ v_ws,
    const float* __restrict__ Wqk, short8* __restrict__ wqk_bf)
{
    const int t = threadIdx.x;
    if (blockIdx.x == NB * NN / 8) {
        if (t < 64) {
            const int lane = t;
            const int n = lane & 15;
            #pragma unroll
            for (int ks = 0; ks < 8; ++ks) {
                short8 v;
                #pragma unroll
                for (int q = 0; q < 8; ++q) {
                    const int k = ks * 32 + ((lane >> 4) & 3) * 8 + q;
                    v[q] = (n < 8) ? (short)f2bf(Wqk[k * NHEADS + n]) : (short)0;
                }
                wqk_bf[ks * 64 + lane] = v;
            }
        }
        return;
    }

    __shared__ float srow[8][NH];
    const int row0 = blockIdx.x * 8;
    #pragma unroll
    for (int r = 0; r < 8; ++r) srow[r][t] = S[(size_t)(row0 + r) * NH + t];
    __syncthreads();

    float acc[8];
    #pragma unroll
    for (int r = 0; r < 8; ++r) acc[r] = 0.0f;
    for (int e = 0; e < NH; e += 4) {
        const float w0 = Wv[(size_t)(e + 0) * NH + t];
        const float w1 = Wv[(size_t)(e + 1) * NH + t];
        const float w2 = Wv[(size_t)(e + 2) * NH + t];
        const float w3 = Wv[(size_t)(e + 3) * NH + t];
        #pragma unroll
        for (int r = 0; r < 8; ++r) {
            const float4 x4 = *(const float4*)&srow[r][e];
            acc[r] = fmaf(x4.x, w0, fmaf(x4.y, w1, fmaf(x4.z, w2, fmaf(x4.w, w3, acc[r]))));
        }
    }
    const float bvc = bv[t];
    const int h = t >> 5, d = t & 31;
    const int b = row0 / NN;
    const int jbase = row0 & (NN - 1);
    #pragma unroll
    for (int r = 0; r < 8; ++r)
        v_ws[((size_t)(b * NHEADS + h) * NN + (size_t)(jbase + r)) * NSUBH + d] = acc[r] + bvc;
}

// ---------------------------------------------------------------------------
// Kernel B (FUSED): scores (MFMA, NT loads) + softmax + attn write + ctx.
// Identical to round-13 except the attn P-write is a non-temporal store
// (attn is final output, never re-read by any kernel).
// ---------------------------------------------------------------------------
__global__ __launch_bounds__(256, 3) void attn_fused_kernel(
    const float* __restrict__ T, const short8* __restrict__ wqk_bf,
    const int* __restrict__ masks, const float* __restrict__ v_ws,
    float* __restrict__ attn, float* __restrict__ ctx_out)
{
    __shared__ unsigned short tlds[4 * 16 * 256];   // 32 KB: 4 wave slices
    __shared__ float sc2[NHEADS][516];              // 16.5 KB scores/P
    __shared__ float maddv[NN];                     // 2 KB
    const int t = threadIdx.x;
    const int lane = t & 63, wv = t >> 6;
    const int bi = blockIdx.x;
    const int b = bi >> 9, i = bi & (NN - 1);

    const int mi = masks[b * NN + i];
    for (int j = t; j < NN; j += 256)
        maddv[j] = (mi != 0 && masks[b * NN + j] != 0) ? 0.0f : -1000.0f;

    // B-fragments from pre-packed global (L2-hot)
    short8 bfrag[8];
    #pragma unroll
    for (int ks = 0; ks < 8; ++ks) bfrag[ks] = wqk_bf[ks * 64 + lane];

    const fvec4* Tv = (const fvec4*)(T + (size_t)bi * NN * NH);
    char* slice = (char*)tlds + wv * 8192;          // wave-private 16-row slice
    const int h = lane & 15;
    const int jrl = lane & 15;

    for (int tile = 0; tile < 8; ++tile) {
        const int jb = wv * 128 + tile * 16;
        // 1. 16 dense NT row-loads (1KB contiguous per wave-instr)
        fvec4 ga[16];
        #pragma unroll
        for (int r = 0; r < 16; ++r)
            ga[r] = __builtin_nontemporal_load(&Tv[(size_t)(jb + r) * 64 + lane]);
        // 2. cvt + stage into wave slice (uniform row per instr, swizzled)
        #pragma unroll
        for (int r = 0; r < 16; ++r) {
            unsigned short v[4];
            v[0] = f2bf(ga[r][0]); v[1] = f2bf(ga[r][1]);
            v[2] = f2bf(ga[r][2]); v[3] = f2bf(ga[r][3]);
            const int byte = (r * 512 + lane * 8) ^ ((r & 7) << 4);
            *(uint2*)(slice + byte) = *(const uint2*)v;
        }
        // 3. 8x mfma 16x16x32 (intra-wave ds ordering, no barrier)
        f32x4 acc = {0.0f, 0.0f, 0.0f, 0.0f};
        #pragma unroll
        for (int ks = 0; ks < 8; ++ks) {
            const int byte = (jrl * 512 + ks * 64 + (lane >> 4) * 16) ^ ((jrl & 7) << 4);
            const short8 af = *(const short8*)(slice + byte);
            acc = __builtin_amdgcn_mfma_f32_16x16x32_bf16(af, bfrag[ks], acc, 0, 0, 0);
        }
        // 4. C-frag -> LDS scores: lane holds col h (<8 valid), rows j0..j0+3
        if (h < 8) {
            const int j0 = jb + (lane >> 4) * 4;
            *(float4*)&sc2[h][j0] = make_float4(acc[0], acc[1], acc[2], acc[3]);
        }
    }
    __syncthreads();

    // -------- softmax per head (32 threads/head), from LDS --------
    const int sh = t >> 5;
    const int l32 = t & 31;
    float* arow = attn + ((size_t)(b * NHEADS + sh) * NN + i) * NN;

    float vals[16];
    float m = -1e30f;
    #pragma unroll
    for (int k = 0; k < 4; ++k) {
        const int j0 = 4 * l32 + 128 * k;
        float4 s4 = *(const float4*)&sc2[sh][j0];
        const float4 m4 = *(const float4*)&maddv[j0];
        s4.x += m4.x; s4.y += m4.y; s4.z += m4.z; s4.w += m4.w;
        vals[4 * k + 0] = s4.x; vals[4 * k + 1] = s4.y;
        vals[4 * k + 2] = s4.z; vals[4 * k + 3] = s4.w;
        m = fmaxf(m, fmaxf(fmaxf(s4.x, s4.y), fmaxf(s4.z, s4.w)));
    }
    #pragma unroll
    for (int off = 16; off >= 1; off >>= 1) m = fmaxf(m, __shfl_xor(m, off, 32));
    float sum = 0.0f;
    #pragma unroll
    for (int k = 0; k < 16; ++k) {
        const float e = __expf(vals[k] - m);
        vals[k] = e;
        sum += e;
    }
    #pragma unroll
    for (int off = 16; off >= 1; off >>= 1) sum += __shfl_xor(sum, off, 32);
    const float inv = 1.0f / sum;
    #pragma unroll
    for (int k = 0; k < 4; ++k) {
        const int j0 = 4 * l32 + 128 * k;
        fvec4 p4;
        p4[0] = vals[4 * k + 0] * inv; p4[1] = vals[4 * k + 1] * inv;
        p4[2] = vals[4 * k + 2] * inv; p4[3] = vals[4 * k + 3] * inv;
        __builtin_nontemporal_store(p4, (fvec4*)&arow[j0]);   // final output
        *(float4*)&sc2[sh][j0] = *(float4*)&p4;
    }
    __syncthreads();

    // -------- ctx[h][d] = sum_j P[h][j] * v[b,h,j,d] --------
    const int d = l32;
    const float* vp = v_ws + (size_t)(b * NHEADS + sh) * NN * NSUBH + d;
    float acc = 0.0f;
    #pragma unroll 8
    for (int j = 0; j < NN; ++j)
        acc = fmaf(sc2[sh][j], vp[(size_t)j * NSUBH], acc);
    ctx_out[(size_t)(b * NN + i) * NH + sh * NSUBH + d] = acc;
}

// ---------------------------------------------------------------------------
// Kernel C: tail. x=relu(ctx·Wo+bo); x1=LN(S+x); y=relu(x1·W1+b1)·W2+b2;
// out=LN(x1+y). Identical to round-13 except out uses NT stores.
// ---------------------------------------------------------------------------
__global__ __launch_bounds__(256) void tail_kernel(
    const float* __restrict__ ctx, const float* __restrict__ S,
    const float* __restrict__ Wo, const float* __restrict__ bo,
    const float* __restrict__ g0, const float* __restrict__ beta0,
    const float* __restrict__ W1, const float* __restrict__ b1,
    const float* __restrict__ W2, const float* __restrict__ b2,
    const float* __restrict__ g1, const float* __restrict__ beta1,
    float* __restrict__ out)
{
    __shared__ float xin[8][NH];
    __shared__ float x1[8][NH];
    __shared__ float ybuf[8][NFF];
    const int t = threadIdx.x;
    const int row0 = blockIdx.x * 8;

    #pragma unroll
    for (int r = 0; r < 8; ++r) xin[r][t] = ctx[(size_t)(row0 + r) * NH + t];
    __syncthreads();

    // GEMM1: ctx @ Wo
    float acc[8];
    #pragma unroll
    for (int r = 0; r < 8; ++r) acc[r] = 0.0f;
    for (int e = 0; e < NH; e += 4) {
        const float w0 = Wo[(size_t)(e + 0) * NH + t];
        const float w1 = Wo[(size_t)(e + 1) * NH + t];
        const float w2 = Wo[(size_t)(e + 2) * NH + t];
        const float w3 = Wo[(size_t)(e + 3) * NH + t];
        #pragma unroll
        for (int r = 0; r < 8; ++r) {
            const float4 x4 = *(const float4*)&xin[r][e];
            acc[r] = fmaf(x4.x, w0, fmaf(x4.y, w1, fmaf(x4.z, w2, fmaf(x4.w, w3, acc[r]))));
        }
    }
    const float boc = bo[t];
    #pragma unroll
    for (int r = 0; r < 8; ++r) {
        const float xv = fmaxf(acc[r] + boc, 0.0f);
        x1[r][t] = S[(size_t)(row0 + r) * NH + t] + xv;
    }
    __syncthreads();

    // LN0 (in place on x1)
    {
        const int wv = t >> 6, ln = t & 63;
        #pragma unroll
        for (int rr = 0; rr < 2; ++rr) {
            const int r = wv * 2 + rr;
            float s1 = 0.0f, s2 = 0.0f;
            #pragma unroll
            for (int k = 0; k < 4; ++k) {
                const float z = x1[r][ln + 64 * k];
                s1 += z; s2 += z * z;
            }
            #pragma unroll
            for (int off = 32; off >= 1; off >>= 1) {
                s1 += __shfl_xor(s1, off);
                s2 += __shfl_xor(s2, off);
            }
            const float mu = s1 * (1.0f / NH);
            const float rsig = rsqrtf(s2 * (1.0f / NH) - mu * mu + LNEPS);
            #pragma unroll
            for (int k = 0; k < 4; ++k) {
                const int c = ln + 64 * k;
                x1[r][c] = (x1[r][c] - mu) * rsig * g0[c] + beta0[c];
            }
        }
    }
    __syncthreads();

    // GEMM2: x1 @ W1 (+b1, relu) -> ybuf
    float acc2[8][4];
    #pragma unroll
    for (int r = 0; r < 8; ++r)
        #pragma unroll
        for (int q = 0; q < 4; ++q) acc2[r][q] = 0.0f;
    for (int e = 0; e < NH; e += 4) {
        float4 x4[8];
        #pragma unroll
        for (int r = 0; r < 8; ++r) x4[r] = *(const float4*)&x1[r][e];
        #pragma unroll
        for (int q = 0; q < 4; ++q) {
            const float* wc = W1 + (size_t)e * NFF + (t + 256 * q);
            const float w0 = wc[0 * NFF], w1 = wc[1 * NFF], w2 = wc[2 * NFF], w3 = wc[3 * NFF];
            #pragma unroll
            for (int r = 0; r < 8; ++r)
                acc2[r][q] = fmaf(x4[r].x, w0, fmaf(x4[r].y, w1, fmaf(x4[r].z, w2, fmaf(x4[r].w, w3, acc2[r][q]))));
        }
    }
    #pragma unroll
    for (int q = 0; q < 4; ++q) {
        const float b1c = b1[t + 256 * q];
        #pragma unroll
        for (int r = 0; r < 8; ++r)
            ybuf[r][t + 256 * q] = fmaxf(acc2[r][q] + b1c, 0.0f);
    }
    __syncthreads();

    // GEMM3: ybuf @ W2 (+b2) + x1 residual
    float acc3[8];
    #pragma unroll
    for (int r = 0; r < 8; ++r) acc3[r] = 0.0f;
    for (int f = 0; f < NFF; f += 4) {
        const float w0 = W2[(size_t)(f + 0) * NH + t];
        const float w1 = W2[(size_t)(f + 1) * NH + t];
        const float w2 = W2[(size_t)(f + 2) * NH + t];
        const float w3 = W2[(size_t)(f + 3) * NH + t];
        #pragma unroll
        for (int r = 0; r < 8; ++r) {
            const float4 y4 = *(const float4*)&ybuf[r][f];
            acc3[r] = fmaf(y4.x, w0, fmaf(y4.y, w1, fmaf(y4.z, w2, fmaf(y4.w, w3, acc3[r]))));
        }
    }
    const float b2c = b2[t];
    #pragma unroll
    for (int r = 0; r < 8; ++r)
        xin[r][t] = x1[r][t] + acc3[r] + b2c;
    __syncthreads();

    // LN1 -> out (NT stores; out never re-read)
    {
        const int wv = t >> 6, ln = t & 63;
        #pragma unroll
        for (int rr = 0; rr < 2; ++rr) {
            const int r = wv * 2 + rr;
            float s1 = 0.0f, s2 = 0.0f;
            #pragma unroll
            for (int k = 0; k < 4; ++k) {
                const float z = xin[r][ln + 64 * k];
                s1 += z; s2 += z * z;
            }
            #pragma unroll
            for (int off = 32; off >= 1; off >>= 1) {
                s1 += __shfl_xor(s1, off);
                s2 += __shfl_xor(s2, off);
            }
            const float mu = s1 * (1.0f / NH);
            const float rsig = rsqrtf(s2 * (1.0f / NH) - mu * mu + LNEPS);
            #pragma unroll
            for (int k = 0; k < 4; ++k) {
                const int c = ln + 64 * k;
                const float o = (xin[r][c] - mu) * rsig * g1[c] + beta1[c];
                __builtin_nontemporal_store(o, &out[(size_t)(row0 + r) * NH + c]);
            }
        }
    }
}

// ---------------------------------------------------------------------------
extern "C" void kernel_launch(void* const* d_in, const int* in_sizes, int n_in,
                              void* d_out, int out_size, void* d_ws, size_t ws_size,
                              hipStream_t stream) {
    const float* S     = (const float*)d_in[0];
    const float* T     = (const float*)d_in[1];
    const int*   masks = (const int*)  d_in[2];
    const float* Wqk   = (const float*)d_in[3];
    const float* Wv    = (const float*)d_in[4];
    const float* bv    = (const float*)d_in[5];
    const float* Wo    = (const float*)d_in[6];
    const float* bo    = (const float*)d_in[7];
    const float* g0    = (const float*)d_in[8];
    const float* beta0 = (const float*)d_in[9];
    const float* W1    = (const float*)d_in[10];
    const float* b1    = (const float*)d_in[11];
    const float* W2    = (const float*)d_in[12];
    const float* b2    = (const float*)d_in[13];
    const float* g1    = (const float*)d_in[14];
    const float* beta1 = (const float*)d_in[15];

    float* out      = (float*)d_out;
    float* attn_out = out + (size_t)NB * NN * NH;   // attn region
    float* v_ws     = (float*)d_ws;                 // 2 MB
    short8* wqk_bf  = (short8*)((char*)d_ws + (size_t)NB * NHEADS * NN * NSUBH * 4);
    float* ctx      = out;                          // reuse out region as scratch

    vproj_kernel<<<NB * NN / 8 + 1, 256, 0, stream>>>(S, Wv, bv, v_ws, Wqk, wqk_bf);
    attn_fused_kernel<<<NB * NN, 256, 0, stream>>>(T, wqk_bf, masks, v_ws,
                                                   attn_out, ctx);
    tail_kernel<<<NB * NN / 8, 256, 0, stream>>>(ctx, S, Wo, bo, g0, beta0,
                                                 W1, b1, W2, b2, g1, beta1, out);
}